// Round 2
// baseline (2323.864 us; speedup 1.0000x reference)
//
#include <hip/hip_runtime.h>
#include <hip/hip_bf16.h>

typedef __hip_bfloat16 bf16;
typedef __attribute__((ext_vector_type(8))) short short8;
typedef __attribute__((ext_vector_type(4))) float floatx4;

#define NB 32
#define NC 512   // channels / attention sequence axis
#define ND 512   // spatial / feature axis (conv dim, LN dim)
#define NDH 64
#define NFF 2048
#define KW 7

__device__ __forceinline__ float bf2f(bf16 v) { return __bfloat162float(v); }
__device__ __forceinline__ bf16 f2bf(float f) { return __float2bfloat16(f); }

typedef __attribute__((address_space(3))) unsigned lds_u32;
typedef __attribute__((address_space(1))) const unsigned glb_u32;
// async 16B/lane global->LDS; lds dest = base + lane*16 (wave-uniform base)
__device__ __forceinline__ void async_copy16(void* lds_dst, const void* gsrc) {
  __builtin_amdgcn_global_load_lds((glb_u32*)gsrc, (lds_u32*)lds_dst, 16, 0, 0);
}

// ---- conv-weight transpose: W (512,512,7) f32 -> Wt[tap][co][ci] bf16
__global__ __launch_bounds__(256) void k_transpose_w(const float* __restrict__ w,
                                                     bf16* __restrict__ wt) {
  int idx = blockIdx.x * 256 + threadIdx.x;
  if (idx >= NC * NC) return;
  int co = idx >> 9, ci = idx & 511;
#pragma unroll
  for (int t = 0; t < KW; ++t)
    wt[(size_t)t * NC * NC + co * NC + ci] = f2bf(w[(size_t)co * NC * KW + (size_t)ci * KW + t]);
}

// ---- batched 2D transpose f32 -> bf16 : dst[z][c][r] = src[z][r][c]
__global__ __launch_bounds__(256) void k_transpose2d(const float* __restrict__ src,
                                                     bf16* __restrict__ dst,
                                                     int R, int Ccols) {
  __shared__ bf16 t[32][33];
  int bc = blockIdx.x * 32, br = blockIdx.y * 32;
  size_t so = (size_t)blockIdx.z * R * Ccols;
  int tx = threadIdx.x & 31, ty = threadIdx.x >> 5;
#pragma unroll
  for (int i = 0; i < 32; i += 8)
    t[ty + i][tx] = f2bf(src[so + (size_t)(br + ty + i) * Ccols + bc + tx]);
  __syncthreads();
#pragma unroll
  for (int i = 0; i < 32; i += 8)
    dst[so + (size_t)(bc + ty + i) * R + br + tx] = t[tx][ty + i];
}

// ---- causal conv over spatial axis d as 7-tap shifted GEMM, contracting ci.
// Input Xt[b][d][ci] (transposed, ci-contiguous). Wt[tap][co][ci].
// TRANS_OUT=false (F1): Y[b][co][d] = outScale*(conv + bias[co])   (normal)
// TRANS_OUT=true  (F2): Y[b][d][co] = outScale*(conv + bias[co])   (transposed)
// Tile: 128 co x 64 d, 4 waves (each: full 128 co x 16 d). X staged via
// global_load_lds (16B, XOR-swizzled segs -> 2-way banks = free); W frags
// direct from global (L2-resident). 8 MFMA per ds_read_b128.
template <bool TRANS_OUT>
__global__ __launch_bounds__(256, 4) void k_conv(const bf16* __restrict__ Xt,
                                                 const bf16* __restrict__ Wt,
                                                 const float* __restrict__ bias,
                                                 bf16* __restrict__ Y, float outScale,
                                                 const bf16* __restrict__ zp) {
  __shared__ __align__(16) bf16 Xs[80 * 32];  // 80 rows (d0-6..d0+73) x 32 ci, 64B rows
  const int d0 = blockIdx.x * 64;
  const int co0 = blockIdx.y * 128;
  const int b = blockIdx.z;
  const int tid = threadIdx.x, lane = tid & 63, wave = tid >> 6;
  const int m16 = lane & 15, qd = lane >> 4;
  const int wd = wave * 16;

  const bf16* xb = Xt + (size_t)b * ND * NC;

  // staging slot 0: instr index = wave (rows wave*16..+15); slot 1 (wave 0): instr 4
  const bf16 *gb0, *gb1;
  bf16 *lb0, *lb1;
  bool ok0, ok1;
  const bool has2 = (wave == 0);
  {
    int r = wave * 16 + (lane >> 2);
    int seg = (lane & 3) ^ ((r >> 1) & 3);
    int d = d0 - 6 + r;
    ok0 = (d >= 0) && (d < ND);
    gb0 = xb + (ptrdiff_t)d * NC + seg * 8;
    lb0 = Xs + wave * 512;
  }
  {
    int r = 64 + (lane >> 2);
    int seg = (lane & 3) ^ ((r >> 1) & 3);
    int d = d0 - 6 + r;
    ok1 = (d >= 0) && (d < ND);
    gb1 = xb + (ptrdiff_t)d * NC + seg * 8;
    lb1 = Xs + 4 * 512;
  }

  floatx4 acc[8];
  const floatx4 zero = {0.f, 0.f, 0.f, 0.f};
#pragma unroll
  for (int i = 0; i < 8; ++i) acc[i] = zero;

  for (int cs = 0; cs < 16; ++cs) {
    __syncthreads();
    async_copy16(lb0, ok0 ? gb0 + cs * 32 : zp);
    if (has2) async_copy16(lb1, ok1 ? gb1 + cs * 32 : zp);
    __syncthreads();
    const bf16* wb = Wt + (size_t)co0 * NC + cs * 32 + (size_t)m16 * NC + qd * 8;
#pragma unroll
    for (int tap = 0; tap < KW; ++tap) {
      int xr = wd + m16 + tap;
      int ps = qd ^ ((xr >> 1) & 3);
      short8 xf = *reinterpret_cast<const short8*>(Xs + xr * 32 + ps * 8);
      const bf16* wp = wb + (size_t)tap * NC * NC;
#pragma unroll
      for (int i = 0; i < 8; ++i) {
        short8 wf = *reinterpret_cast<const short8*>(wp + (size_t)(i * 16) * NC);
        if (TRANS_OUT)
          acc[i] = __builtin_amdgcn_mfma_f32_16x16x32_bf16(xf, wf, acc[i], 0, 0, 0);
        else
          acc[i] = __builtin_amdgcn_mfma_f32_16x16x32_bf16(wf, xf, acc[i], 0, 0, 0);
      }
    }
  }

  if (!TRANS_OUT) {
    // C[m=co][n=d]: row co = co0+i*16+qd*4+r, col d = d0+wd+m16
    bf16* yb = Y + (size_t)b * NC * ND;
    int dcol = d0 + wd + m16;
#pragma unroll
    for (int i = 0; i < 8; ++i) {
      int cobase = co0 + i * 16 + qd * 4;
#pragma unroll
      for (int r = 0; r < 4; ++r) {
        float v = (acc[i][r] + bias[cobase + r]) * outScale;
        yb[(size_t)(cobase + r) * ND + dcol] = f2bf(v);
      }
    }
  } else {
    // C[m=d][n=co]: row d = d0+wd+qd*4+r, col co = co0+i*16+m16
    bf16* yb = Y + (size_t)b * ND * NC;
    int drow = d0 + wd + qd * 4;
#pragma unroll
    for (int i = 0; i < 8; ++i) {
      float bv = bias[co0 + i * 16 + m16];
      int ccol = co0 + i * 16 + m16;
#pragma unroll
      for (int r = 0; r < 4; ++r) {
        float v = (acc[i][r] + bv) * outScale;
        yb[(size_t)(drow + r) * NC + ccol] = f2bf(v);
      }
    }
  }
}

// ---- row layernorm over last dim (512)
__global__ __launch_bounds__(256, 4) void k_layernorm(const bf16* __restrict__ x,
                                                      const float* __restrict__ gamma,
                                                      const float* __restrict__ beta,
                                                      bf16* __restrict__ y) {
  int row = blockIdx.x * 4 + (threadIdx.x >> 6);
  int lane = threadIdx.x & 63;
  const bf16* xr = x + (size_t)row * ND + lane * 8;
  uint4 raw = *reinterpret_cast<const uint4*>(xr);
  const bf16* rp = reinterpret_cast<const bf16*>(&raw);
  float v[8];
#pragma unroll
  for (int j = 0; j < 8; ++j) v[j] = bf2f(rp[j]);
  float s = 0.f;
#pragma unroll
  for (int j = 0; j < 8; ++j) s += v[j];
#pragma unroll
  for (int m = 32; m >= 1; m >>= 1) s += __shfl_xor(s, m, 64);
  float mean = s * (1.f / 512.f);
  float ss = 0.f;
#pragma unroll
  for (int j = 0; j < 8; ++j) { float dd = v[j] - mean; ss += dd * dd; }
#pragma unroll
  for (int m = 32; m >= 1; m >>= 1) ss += __shfl_xor(ss, m, 64);
  float rden = 1.f / (sqrtf(ss * (1.f / 511.f)) + 1e-6f);
  __align__(16) bf16 outv[8];
#pragma unroll
  for (int j = 0; j < 8; ++j)
    outv[j] = f2bf(gamma[lane * 8 + j] * (v[j] - mean) * rden + beta[lane * 8 + j]);
  *reinterpret_cast<uint4*>(y + (size_t)row * ND + lane * 8) = *reinterpret_cast<uint4*>(outv);
}

// ---- column layernorm: x[b][d][c] (normalize over d rows per column c),
// gamma/beta indexed by d. y[b][d][c].
__global__ __launch_bounds__(256, 2) void k_layernorm_col(const bf16* __restrict__ x,
                                                          const float* __restrict__ gamma,
                                                          const float* __restrict__ beta,
                                                          bf16* __restrict__ y) {
  __shared__ float red[2][8][256];
  __shared__ float mS[256], rS[256];
  const int b = blockIdx.y;
  const int c0 = blockIdx.x * 256;
  const int t = threadIdx.x;
  const int g = t & 31, sl = t >> 5;
  const bf16* xb = x + (size_t)b * ND * NC + c0 + g * 8;
  float fs[8], fq[8];
#pragma unroll
  for (int j = 0; j < 8; ++j) { fs[j] = 0.f; fq[j] = 0.f; }
  for (int i = 0; i < 64; ++i) {
    int r = sl * 64 + i;
    uint4 raw = *reinterpret_cast<const uint4*>(xb + (size_t)r * NC);
    const bf16* rp = reinterpret_cast<const bf16*>(&raw);
#pragma unroll
    for (int j = 0; j < 8; ++j) { float v = bf2f(rp[j]); fs[j] += v; fq[j] += v * v; }
  }
#pragma unroll
  for (int j = 0; j < 8; ++j) { red[0][sl][g * 8 + j] = fs[j]; red[1][sl][g * 8 + j] = fq[j]; }
  __syncthreads();
  {
    float s = 0.f, q = 0.f;
#pragma unroll
    for (int s2 = 0; s2 < 8; ++s2) { s += red[0][s2][t]; q += red[1][s2][t]; }
    float mean = s * (1.f / 512.f);
    float var = fmaxf((q - 512.f * mean * mean) * (1.f / 511.f), 0.f);
    mS[t] = mean;
    rS[t] = 1.f / (sqrtf(var) + 1e-6f);
  }
  __syncthreads();
  float mv[8], rv[8];
#pragma unroll
  for (int j = 0; j < 8; ++j) { mv[j] = mS[g * 8 + j]; rv[j] = rS[g * 8 + j]; }
  bf16* yb = y + (size_t)b * ND * NC + c0 + g * 8;
  for (int i = 0; i < 64; ++i) {
    int r = sl * 64 + i;
    uint4 raw = *reinterpret_cast<const uint4*>(xb + (size_t)r * NC);
    const bf16* rp = reinterpret_cast<const bf16*>(&raw);
    float gr = gamma[r], br = beta[r];
    __align__(16) bf16 ov[8];
#pragma unroll
    for (int j = 0; j < 8; ++j) ov[j] = f2bf(gr * (bf2f(rp[j]) - mv[j]) * rv[j] + br);
    *reinterpret_cast<uint4*>(yb + (size_t)r * NC) = *reinterpret_cast<uint4*>(ov);
  }
}

// ---- attention: Q,K normal [c][d]; Vt transposed [d][c]; output O^T [d][c].
// Block = (128 q, head, batch), 4 waves x 32 q. S-phase normal; PV computed as
// O^T = Vt * P^T (A=Vt direct global, B=P from wave-private LDS slab).
__global__ __launch_bounds__(256, 3) void k_attention(const bf16* __restrict__ Q,
                                                      const bf16* __restrict__ K,
                                                      const bf16* __restrict__ Vt,
                                                      bf16* __restrict__ OT) {
  __shared__ __align__(16) bf16 Ks[64 * 64];   // [key][dh], 128B rows, XOR-swizzled
  __shared__ __align__(16) bf16 Ps[4][32][72];
  __shared__ float linvS[4][32];
  const int qc = blockIdx.x, h = blockIdx.y, b = blockIdx.z;
  const int tid = threadIdx.x, lane = tid & 63, wave = tid >> 6;
  const int m16 = lane & 15, qd = lane >> 4;
  const size_t base = (size_t)b * NC * ND;   // Q/K [c][d]
  const size_t baseT = (size_t)b * ND * NC;  // Vt/OT [d][c]

  short8 aq[2][2];
#pragma unroll
  for (int ms = 0; ms < 2; ++ms)
#pragma unroll
    for (int ks = 0; ks < 2; ++ks)
      aq[ms][ks] = *reinterpret_cast<const short8*>(
          Q + base + (size_t)(qc * 128 + wave * 32 + ms * 16 + m16) * ND + h * 64 + ks * 32 + qd * 8);

  // K staging slots: 2 instrs per wave, 8 rows each
  const bf16* kg[2];
  bf16* kl[2];
#pragma unroll
  for (int s = 0; s < 2; ++s) {
    int i = wave * 2 + s;
    int row = i * 8 + (lane >> 3);
    int seg = (lane & 7) ^ (row & 7);
    kg[s] = K + base + (size_t)row * ND + h * 64 + seg * 8;
    kl[s] = Ks + i * 512;
  }

  floatx4 oa[4][2];
  const floatx4 zero = {0.f, 0.f, 0.f, 0.f};
#pragma unroll
  for (int i = 0; i < 4; ++i)
#pragma unroll
    for (int j = 0; j < 2; ++j) oa[i][j] = zero;
  float lsum[2][4];
#pragma unroll
  for (int i = 0; i < 2; ++i)
#pragma unroll
    for (int r = 0; r < 4; ++r) lsum[i][r] = 0.f;

  for (int kc = 0; kc < 8; ++kc) {
    __syncthreads();
#pragma unroll
    for (int s = 0; s < 2; ++s) async_copy16(kl[s], kg[s] + (size_t)(kc * 64) * ND);
    __syncthreads();
    // S = Q K^T
    floatx4 sc[2][4];
#pragma unroll
    for (int i = 0; i < 2; ++i)
#pragma unroll
      for (int j = 0; j < 4; ++j) sc[i][j] = zero;
#pragma unroll
    for (int ks = 0; ks < 2; ++ks)
#pragma unroll
      for (int n = 0; n < 4; ++n) {
        int row = n * 16 + m16;
        int phys = (ks * 4 + qd) ^ (row & 7);
        short8 bk = *reinterpret_cast<const short8*>(Ks + row * 64 + phys * 8);
#pragma unroll
        for (int ms = 0; ms < 2; ++ms)
          sc[ms][n] = __builtin_amdgcn_mfma_f32_16x16x32_bf16(aq[ms][ks], bk, sc[ms][n], 0, 0, 0);
      }
#pragma unroll
    for (int ms = 0; ms < 2; ++ms)
#pragma unroll
      for (int n = 0; n < 4; ++n)
#pragma unroll
        for (int r = 0; r < 4; ++r) {
          float p = __expf(sc[ms][n][r] * 0.125f);
          lsum[ms][r] += p;
          Ps[wave][ms * 16 + qd * 4 + r][n * 16 + m16] = f2bf(p);
        }
    // O^T += Vt * P^T
#pragma unroll
    for (int ks = 0; ks < 2; ++ks) {
      short8 bp[2];
#pragma unroll
      for (int j = 0; j < 2; ++j)
        bp[j] = *reinterpret_cast<const short8*>(&Ps[wave][j * 16 + m16][ks * 32 + qd * 8]);
#pragma unroll
      for (int i = 0; i < 4; ++i) {
        short8 av = *reinterpret_cast<const short8*>(
            Vt + baseT + (size_t)(h * 64 + i * 16 + m16) * NC + kc * 64 + ks * 32 + qd * 8);
#pragma unroll
        for (int j = 0; j < 2; ++j)
          oa[i][j] = __builtin_amdgcn_mfma_f32_16x16x32_bf16(av, bp[j], oa[i][j], 0, 0, 0);
      }
    }
  }
#pragma unroll
  for (int ms = 0; ms < 2; ++ms)
#pragma unroll
    for (int r = 0; r < 4; ++r) {
      float t = lsum[ms][r];
      t += __shfl_xor(t, 1, 64);
      t += __shfl_xor(t, 2, 64);
      t += __shfl_xor(t, 4, 64);
      t += __shfl_xor(t, 8, 64);
      if (m16 == 0) linvS[wave][ms * 16 + qd * 4 + r] = 1.f / t;
    }
  __syncthreads();
  float lsc[2];
#pragma unroll
  for (int j = 0; j < 2; ++j) lsc[j] = linvS[wave][j * 16 + m16];
#pragma unroll
  for (int i = 0; i < 4; ++i) {
    int drow = h * 64 + i * 16 + qd * 4;
#pragma unroll
    for (int j = 0; j < 2; ++j) {
      int qcol = qc * 128 + wave * 32 + j * 16 + m16;
#pragma unroll
      for (int r = 0; r < 4; ++r)
        OT[baseT + (size_t)(drow + r) * NC + qcol] = f2bf(oa[i][j][r] * lsc[j]);
    }
  }
}

// ---- GEMM C = A(MxK) * Bt(NxK)^T, bf16 k-contiguous, global_load_lds staging.
// mode 0: Y(bf16) = relu(acc + bias[n]); mode 1: Y(f32) = 2*(acc + bias[n])
__global__ __launch_bounds__(256, 3) void k_gemm_bt(const bf16* __restrict__ A,
                                                    const bf16* __restrict__ Bt,
                                                    const float* __restrict__ bias,
                                                    void* __restrict__ Y,
                                                    int Kdim, int Ndim, int mode) {
  __shared__ __align__(16) bf16 As[128 * 32];
  __shared__ __align__(16) bf16 Bs[128 * 32];
  const int n0 = blockIdx.x * 128, m0 = blockIdx.y * 128;
  const int tid = threadIdx.x, lane = tid & 63, wave = tid >> 6;
  const int wm = (wave & 1) * 64, wn = (wave >> 1) * 64;
  const int m16 = lane & 15, qd = lane >> 4;

  const bf16* gb[4];
  bf16* lb[4];
#pragma unroll
  for (int idx = 0; idx < 4; ++idx) {
    int s = wave + idx * 4;
    int which = s >> 3;  // 0 = A, 1 = B
    int i8 = s & 7;
    int row = i8 * 16 + (lane >> 2);
    int seg = (lane & 3) ^ ((row >> 1) & 3);
    const bf16* src = which ? (Bt + (size_t)(n0 + row) * Kdim) : (A + (size_t)(m0 + row) * Kdim);
    gb[idx] = src + seg * 8;
    lb[idx] = (which ? Bs : As) + i8 * 512;
  }

  floatx4 acc[4][4];
  const floatx4 zero = {0.f, 0.f, 0.f, 0.f};
#pragma unroll
  for (int i = 0; i < 4; ++i)
#pragma unroll
    for (int j = 0; j < 4; ++j) acc[i][j] = zero;

  for (int ks = 0; ks < Kdim / 32; ++ks) {
    __syncthreads();
#pragma unroll
    for (int idx = 0; idx < 4; ++idx) async_copy16(lb[idx], gb[idx] + ks * 32);
    __syncthreads();
    short8 af[4], bfv[4];
#pragma unroll
    for (int i = 0; i < 4; ++i) {
      int ra = wm + i * 16 + m16;
      af[i] = *reinterpret_cast<const short8*>(As + ra * 32 + (qd ^ ((ra >> 1) & 3)) * 8);
      int rb = wn + i * 16 + m16;
      bfv[i] = *reinterpret_cast<const short8*>(Bs + rb * 32 + (qd ^ ((rb >> 1) & 3)) * 8);
    }
#pragma unroll
    for (int j = 0; j < 4; ++j)
#pragma unroll
      for (int i = 0; i < 4; ++i)
        acc[i][j] = __builtin_amdgcn_mfma_f32_16x16x32_bf16(af[i], bfv[j], acc[i][j], 0, 0, 0);
  }
#pragma unroll
  for (int i = 0; i < 4; ++i) {
    int m = m0 + wm + i * 16 + qd * 4;
#pragma unroll
    for (int j = 0; j < 4; ++j) {
      int n = n0 + wn + j * 16 + m16;
      float bv = bias[n];
#pragma unroll
      for (int r = 0; r < 4; ++r) {
        float v = acc[i][j][r] + bv;
        size_t idx = (size_t)(m + r) * Ndim + n;
        if (mode == 0)
          ((bf16*)Y)[idx] = f2bf(fmaxf(v, 0.f));
        else
          ((float*)Y)[idx] = 2.f * v;
      }
    }
  }
}

extern "C" void kernel_launch(void* const* d_in, const int* in_sizes, int n_in,
                              void* d_out, int out_size, void* d_ws, size_t ws_size,
                              hipStream_t stream) {
  (void)in_sizes; (void)n_in; (void)out_size; (void)ws_size;
  const float* x         = (const float*)d_in[0];
  const float* w_conv_in = (const float*)d_in[1];
  const float* b_conv_in = (const float*)d_in[2];
  const float* wq        = (const float*)d_in[3];
  const float* bq        = (const float*)d_in[4];
  const float* wk        = (const float*)d_in[5];
  const float* bk        = (const float*)d_in[6];
  const float* wv        = (const float*)d_in[7];
  const float* bv        = (const float*)d_in[8];
  const float* wo        = (const float*)d_in[9];
  const float* bo        = (const float*)d_in[10];
  const float* ln0_g     = (const float*)d_in[11];
  const float* ln0_b     = (const float*)d_in[12];
  const float* ln1_g     = (const float*)d_in[13];
  const float* ln1_b     = (const float*)d_in[14];
  const float* w1        = (const float*)d_in[15];
  const float* b1        = (const float*)d_in[16];
  const float* w2        = (const float*)d_in[17];
  const float* b2        = (const float*)d_in[18];

  char* ws = (char*)d_ws;
  const size_t WT  = (size_t)KW * NC * NC * 2;
  const size_t W1T = (size_t)NFF * ND * 2;
  const size_t ACT = (size_t)NB * NC * ND * 2;
  size_t off = 0;
  bf16* zp    = (bf16*)(ws + off); off += 256;
  bf16* wt_in = (bf16*)(ws + off); off += WT;
  bf16* wt_q  = (bf16*)(ws + off); off += WT;
  bf16* wt_k  = (bf16*)(ws + off); off += WT;
  bf16* wt_v  = (bf16*)(ws + off); off += WT;
  bf16* wt_o  = (bf16*)(ws + off); off += WT;
  bf16* w1t   = (bf16*)(ws + off); off += W1T;
  bf16* w2t   = (bf16*)(ws + off); off += W1T;
  bf16* T1    = (bf16*)(ws + off); off += ACT;  // xT -> K -> (dead)
  bf16* T2    = (bf16*)(ws + off); off += ACT;  // qiT -> hn
  bf16* T3    = (bf16*)(ws + off); off += ACT;  // xnT -> aoT
  bf16* T4    = (bf16*)(ws + off); off += ACT;  // Q -> h1
  bf16* T5    = (bf16*)(ws + off); off += ACT;  // Vt
  bf16* mid   = (bf16*)(ws + off); off += (size_t)NB * NC * NFF * 2;

  hipMemsetAsync(zp, 0, 256, stream);

  // weight prep
  k_transpose_w<<<1024, 256, 0, stream>>>(w_conv_in, wt_in);
  k_transpose_w<<<1024, 256, 0, stream>>>(wq, wt_q);
  k_transpose_w<<<1024, 256, 0, stream>>>(wk, wt_k);
  k_transpose_w<<<1024, 256, 0, stream>>>(wv, wt_v);
  k_transpose_w<<<1024, 256, 0, stream>>>(wo, wt_o);
  k_transpose2d<<<dim3(NFF / 32, ND / 32, 1), 256, 0, stream>>>(w1, w1t, ND, NFF);
  k_transpose2d<<<dim3(ND / 32, NFF / 32, 1), 256, 0, stream>>>(w2, w2t, NFF, ND);
  // xT[b][d][c] from x[b][c][d]
  k_transpose2d<<<dim3(ND / 32, NC / 32, NB), 256, 0, stream>>>(x, T1, NC, ND);

  dim3 cgrid(ND / 64, NC / 128, NB);
  // query_in^T (F2)
  k_conv<true><<<cgrid, 256, 0, stream>>>(T1, wt_in, b_conv_in, T2, 1.f, zp);
  // xn^T = colLN(query_in^T)
  k_layernorm_col<<<dim3(NC / 256, NB), 256, 0, stream>>>(T2, ln0_g, ln0_b, T3);
  // Q (F1 normal), K (F1 normal), Vt (F2 transposed)
  k_conv<false><<<cgrid, 256, 0, stream>>>(T2, wt_q, bq, T4, 1.f, zp);
  k_conv<false><<<cgrid, 256, 0, stream>>>(T3, wt_k, bk, T1, 1.f, zp);
  k_conv<true><<<cgrid, 256, 0, stream>>>(T3, wt_v, bv, T5, 1.f, zp);
  // attn -> O^T
  k_attention<<<dim3(NC / 128, 8, NB), 256, 0, stream>>>(T4, T1, T5, T3);
  // h1 = 2*(conv_o(O^T) + bo)  (F1 normal)
  k_conv<false><<<cgrid, 256, 0, stream>>>(T3, wt_o, bo, T4, 2.f, zp);
  // hn = rowLN(h1)
  k_layernorm<<<NB * NC / 4, 256, 0, stream>>>(T4, ln1_g, ln1_b, T2);
  // ffn
  k_gemm_bt<<<dim3(NFF / 128, NB * NC / 128), 256, 0, stream>>>(T2, w1t, b1, mid, ND, NFF, 0);
  k_gemm_bt<<<dim3(ND / 128, NB * NC / 128), 256, 0, stream>>>(mid, w2t, b2, d_out, NFF, ND, 1);
}

// Round 3
// 638.796 us; speedup vs baseline: 3.6379x; 3.6379x over previous
//
#include <hip/hip_runtime.h>
#include <hip/hip_bf16.h>

typedef __hip_bfloat16 bf16;
typedef __attribute__((ext_vector_type(8))) short short8;
typedef __attribute__((ext_vector_type(4))) float floatx4;

#define NB 32
#define NC 512   // channels / attention sequence axis
#define ND 512   // spatial / feature axis (conv dim, LN dim)
#define NDH 64
#define NFF 2048
#define KW 7

__device__ __forceinline__ float bf2f(bf16 v) { return __bfloat162float(v); }
__device__ __forceinline__ bf16 f2bf(float f) { return __float2bfloat16(f); }

typedef __attribute__((address_space(3))) unsigned lds_u32;
typedef __attribute__((address_space(1))) const unsigned glb_u32;
// async 16B/lane global->LDS; lds dest = wave-uniform base + lane*16
__device__ __forceinline__ void async_copy16(void* lds_dst, const void* gsrc) {
  __builtin_amdgcn_global_load_lds((glb_u32*)gsrc, (lds_u32*)lds_dst, 16, 0, 0);
}

// ---- conv-weight transpose: W (512,512,7) f32 -> Wt[tap][co][ci] bf16
__global__ __launch_bounds__(256) void k_transpose_w(const float* __restrict__ w,
                                                     bf16* __restrict__ wt) {
  int idx = blockIdx.x * 256 + threadIdx.x;
  if (idx >= NC * NC) return;
  int co = idx >> 9, ci = idx & 511;
#pragma unroll
  for (int t = 0; t < KW; ++t)
    wt[(size_t)t * NC * NC + co * NC + ci] = f2bf(w[(size_t)co * NC * KW + (size_t)ci * KW + t]);
}

// ---- batched 2D transpose f32 -> bf16 : dst[z][c][r] = src[z][r][c]
__global__ __launch_bounds__(256) void k_transpose2d(const float* __restrict__ src,
                                                     bf16* __restrict__ dst,
                                                     int R, int Ccols) {
  __shared__ bf16 t[32][33];
  int bc = blockIdx.x * 32, br = blockIdx.y * 32;
  size_t so = (size_t)blockIdx.z * R * Ccols;
  int tx = threadIdx.x & 31, ty = threadIdx.x >> 5;
#pragma unroll
  for (int i = 0; i < 32; i += 8)
    t[ty + i][tx] = f2bf(src[so + (size_t)(br + ty + i) * Ccols + bc + tx]);
  __syncthreads();
#pragma unroll
  for (int i = 0; i < 32; i += 8)
    dst[so + (size_t)(bc + ty + i) * R + br + tx] = t[tx][ty + i];
}

// ---- causal conv as 7-tap shifted GEMM, both operands staged in LDS (m97 style).
// Input Xt[b][d][ci] (ci-contiguous). Wt[tap][co][ci].
// Block: 128co x 128d, 4 waves 2x2 (wave = 64co x 64d). BK=32 ci, 16 k-steps.
// Per k-step: phase A stages X rows [d0-6, d0+138) + W taps 0-3, compute;
// phase B stages W taps 4-6, compute. LDS 41KB -> 3 blocks/CU.
// TRANS_OUT=false: Y[b][co][d]; true: Y[b][d][co]. Zero-pad handled via zp page.
template <bool TRANS_OUT>
__global__ __launch_bounds__(256, 3) void k_conv(const bf16* __restrict__ Xt,
                                                 const bf16* __restrict__ Wt,
                                                 const float* __restrict__ bias,
                                                 bf16* __restrict__ Y, float outScale,
                                                 const bf16* __restrict__ zp) {
  __shared__ __align__(16) bf16 Ws[512 * 32];  // 4 taps x 128 co x 32 ci
  __shared__ __align__(16) bf16 Xs[144 * 32];  // rows: d0-6+r, 64B rows, XOR-swizzled
  const int d0 = blockIdx.x * 128;
  const int co0 = blockIdx.y * 128;
  const int b = blockIdx.z;
  const int tid = threadIdx.x, lane = tid & 63, wave = tid >> 6;
  const int m16 = lane & 15, qd = lane >> 4;
  const int wm = (wave & 1) * 64, wn = (wave >> 1) * 64;
  const int l4 = lane >> 2;
  const int seg = (lane & 3) ^ ((l4 >> 1) & 3);

  const bf16* xb = Xt + (size_t)b * ND * NC;
  // per-lane staging bases (scalar per-instr offsets added in-loop)
  const bf16* pw = Wt + (size_t)(co0 + l4) * NC + seg * 8;
  const bf16* pxm = xb + (ptrdiff_t)(d0 - 6 + l4) * NC + seg * 8;
  const bf16* px0 = (d0 == 0 && l4 < 6) ? (zp + seg * 8) : pxm;      // rows 0..5 may be d<0
  const bf16* px8 = (d0 == 384 && l4 >= 6) ? (zp + seg * 8) : pxm;   // rows 134..143 may be d>=512

  floatx4 acc[4][4];
  const floatx4 zero = {0.f, 0.f, 0.f, 0.f};
#pragma unroll
  for (int i = 0; i < 4; ++i)
#pragma unroll
    for (int j = 0; j < 4; ++j) acc[i][j] = zero;

  const int physW = qd ^ ((m16 >> 1) & 3);

  for (int cs = 0; cs < 16; ++cs) {
    const int ko = cs * 32;
    __syncthreads();
    // ---- stage X (9 wave-instrs) + W taps 0..3 (wave w stages tap w, 8 instrs)
    {
      const bf16* s0 = (wave == 0) ? px0 : pxm;
      async_copy16(Xs + wave * 512, s0 + wave * (16 * NC) + ko);
      async_copy16(Xs + (wave + 4) * 512, pxm + (wave + 4) * (16 * NC) + ko);
      if (wave == 0) async_copy16(Xs + 8 * 512, px8 + 8 * (16 * NC) + ko);
      const bf16* pt = pw + (size_t)wave * NC * NC + ko;
#pragma unroll
      for (int q = 0; q < 8; ++q)
        async_copy16(Ws + (wave * 8 + q) * 512, pt + q * (16 * NC));
    }
    __syncthreads();
    // ---- compute taps 0..3
#pragma unroll
    for (int t = 0; t < 4; ++t) {
      short8 wf[4], xf[4];
#pragma unroll
      for (int i = 0; i < 4; ++i)
        wf[i] = *reinterpret_cast<const short8*>(Ws + (t * 128 + wm + i * 16 + m16) * 32 + physW * 8);
      int rb = wn + m16 + t;
      int physX = qd ^ ((rb >> 1) & 3);
#pragma unroll
      for (int j = 0; j < 4; ++j)
        xf[j] = *reinterpret_cast<const short8*>(Xs + (rb + j * 16) * 32 + physX * 8);
#pragma unroll
      for (int i = 0; i < 4; ++i)
#pragma unroll
        for (int j = 0; j < 4; ++j)
          acc[i][j] = TRANS_OUT
              ? __builtin_amdgcn_mfma_f32_16x16x32_bf16(xf[j], wf[i], acc[i][j], 0, 0, 0)
              : __builtin_amdgcn_mfma_f32_16x16x32_bf16(wf[i], xf[j], acc[i][j], 0, 0, 0);
    }
    __syncthreads();
    // ---- stage W taps 4..6 (24 wave-instrs, 6 per wave)
#pragma unroll
    for (int k = 0; k < 6; ++k) {
      int s = wave * 6 + k;
      int tl = s >> 3, q = s & 7;
      async_copy16(Ws + s * 512, pw + (size_t)(tl + 4) * NC * NC + q * (16 * NC) + ko);
    }
    __syncthreads();
    // ---- compute taps 4..6
#pragma unroll
    for (int tl = 0; tl < 3; ++tl) {
      short8 wf[4], xf[4];
#pragma unroll
      for (int i = 0; i < 4; ++i)
        wf[i] = *reinterpret_cast<const short8*>(Ws + (tl * 128 + wm + i * 16 + m16) * 32 + physW * 8);
      int rb = wn + m16 + tl + 4;
      int physX = qd ^ ((rb >> 1) & 3);
#pragma unroll
      for (int j = 0; j < 4; ++j)
        xf[j] = *reinterpret_cast<const short8*>(Xs + (rb + j * 16) * 32 + physX * 8);
#pragma unroll
      for (int i = 0; i < 4; ++i)
#pragma unroll
        for (int j = 0; j < 4; ++j)
          acc[i][j] = TRANS_OUT
              ? __builtin_amdgcn_mfma_f32_16x16x32_bf16(xf[j], wf[i], acc[i][j], 0, 0, 0)
              : __builtin_amdgcn_mfma_f32_16x16x32_bf16(wf[i], xf[j], acc[i][j], 0, 0, 0);
    }
  }

  if (!TRANS_OUT) {
    bf16* yb = Y + (size_t)b * NC * ND;
#pragma unroll
    for (int i = 0; i < 4; ++i) {
      int cobase = co0 + wm + i * 16 + qd * 4;
#pragma unroll
      for (int j = 0; j < 4; ++j) {
        int dcol = d0 + wn + j * 16 + m16;
#pragma unroll
        for (int r = 0; r < 4; ++r) {
          float v = (acc[i][j][r] + bias[cobase + r]) * outScale;
          yb[(size_t)(cobase + r) * ND + dcol] = f2bf(v);
        }
      }
    }
  } else {
    bf16* yb = Y + (size_t)b * ND * NC;
#pragma unroll
    for (int i = 0; i < 4; ++i) {
      int ccol = co0 + wm + i * 16 + m16;
      float bv = bias[ccol];
#pragma unroll
      for (int j = 0; j < 4; ++j) {
        int drow = d0 + wn + j * 16 + qd * 4;
#pragma unroll
        for (int r = 0; r < 4; ++r) {
          float v = (acc[i][j][r] + bv) * outScale;
          yb[(size_t)(drow + r) * NC + ccol] = f2bf(v);
        }
      }
    }
  }
}

// ---- row layernorm over last dim (512)
__global__ __launch_bounds__(256, 4) void k_layernorm(const bf16* __restrict__ x,
                                                      const float* __restrict__ gamma,
                                                      const float* __restrict__ beta,
                                                      bf16* __restrict__ y) {
  int row = blockIdx.x * 4 + (threadIdx.x >> 6);
  int lane = threadIdx.x & 63;
  const bf16* xr = x + (size_t)row * ND + lane * 8;
  uint4 raw = *reinterpret_cast<const uint4*>(xr);
  const bf16* rp = reinterpret_cast<const bf16*>(&raw);
  float v[8];
#pragma unroll
  for (int j = 0; j < 8; ++j) v[j] = bf2f(rp[j]);
  float s = 0.f;
#pragma unroll
  for (int j = 0; j < 8; ++j) s += v[j];
#pragma unroll
  for (int m = 32; m >= 1; m >>= 1) s += __shfl_xor(s, m, 64);
  float mean = s * (1.f / 512.f);
  float ss = 0.f;
#pragma unroll
  for (int j = 0; j < 8; ++j) { float dd = v[j] - mean; ss += dd * dd; }
#pragma unroll
  for (int m = 32; m >= 1; m >>= 1) ss += __shfl_xor(ss, m, 64);
  float rden = 1.f / (sqrtf(ss * (1.f / 511.f)) + 1e-6f);
  __align__(16) bf16 outv[8];
#pragma unroll
  for (int j = 0; j < 8; ++j)
    outv[j] = f2bf(gamma[lane * 8 + j] * (v[j] - mean) * rden + beta[lane * 8 + j]);
  *reinterpret_cast<uint4*>(y + (size_t)row * ND + lane * 8) = *reinterpret_cast<uint4*>(outv);
}

// ---- column layernorm: x[b][d][c] (normalize over d per column c)
__global__ __launch_bounds__(256, 2) void k_layernorm_col(const bf16* __restrict__ x,
                                                          const float* __restrict__ gamma,
                                                          const float* __restrict__ beta,
                                                          bf16* __restrict__ y) {
  __shared__ float red[2][8][256];
  __shared__ float mS[256], rS[256];
  const int b = blockIdx.y;
  const int c0 = blockIdx.x * 256;
  const int t = threadIdx.x;
  const int g = t & 31, sl = t >> 5;
  const bf16* xb = x + (size_t)b * ND * NC + c0 + g * 8;
  float fs[8], fq[8];
#pragma unroll
  for (int j = 0; j < 8; ++j) { fs[j] = 0.f; fq[j] = 0.f; }
  for (int i = 0; i < 64; ++i) {
    int r = sl * 64 + i;
    uint4 raw = *reinterpret_cast<const uint4*>(xb + (size_t)r * NC);
    const bf16* rp = reinterpret_cast<const bf16*>(&raw);
#pragma unroll
    for (int j = 0; j < 8; ++j) { float v = bf2f(rp[j]); fs[j] += v; fq[j] += v * v; }
  }
#pragma unroll
  for (int j = 0; j < 8; ++j) { red[0][sl][g * 8 + j] = fs[j]; red[1][sl][g * 8 + j] = fq[j]; }
  __syncthreads();
  {
    float s = 0.f, q = 0.f;
#pragma unroll
    for (int s2 = 0; s2 < 8; ++s2) { s += red[0][s2][t]; q += red[1][s2][t]; }
    float mean = s * (1.f / 512.f);
    float var = fmaxf((q - 512.f * mean * mean) * (1.f / 511.f), 0.f);
    mS[t] = mean;
    rS[t] = 1.f / (sqrtf(var) + 1e-6f);
  }
  __syncthreads();
  float mv[8], rv[8];
#pragma unroll
  for (int j = 0; j < 8; ++j) { mv[j] = mS[g * 8 + j]; rv[j] = rS[g * 8 + j]; }
  bf16* yb = y + (size_t)b * ND * NC + c0 + g * 8;
  for (int i = 0; i < 64; ++i) {
    int r = sl * 64 + i;
    uint4 raw = *reinterpret_cast<const uint4*>(xb + (size_t)r * NC);
    const bf16* rp = reinterpret_cast<const bf16*>(&raw);
    float gr = gamma[r], br = beta[r];
    __align__(16) bf16 ov[8];
#pragma unroll
    for (int j = 0; j < 8; ++j) ov[j] = f2bf(gr * (bf2f(rp[j]) - mv[j]) * rv[j] + br);
    *reinterpret_cast<uint4*>(yb + (size_t)r * NC) = *reinterpret_cast<uint4*>(ov);
  }
}

// ---- attention: Q,K normal [c][d]; Vt transposed [d][c]; output O^T [d][c].
__global__ __launch_bounds__(256, 3) void k_attention(const bf16* __restrict__ Q,
                                                      const bf16* __restrict__ K,
                                                      const bf16* __restrict__ Vt,
                                                      bf16* __restrict__ OT) {
  __shared__ __align__(16) bf16 Ks[64 * 64];
  __shared__ __align__(16) bf16 Ps[4][32][72];
  __shared__ float linvS[4][32];
  const int qc = blockIdx.x, h = blockIdx.y, b = blockIdx.z;
  const int tid = threadIdx.x, lane = tid & 63, wave = tid >> 6;
  const int m16 = lane & 15, qd = lane >> 4;
  const size_t base = (size_t)b * NC * ND;
  const size_t baseT = (size_t)b * ND * NC;

  short8 aq[2][2];
#pragma unroll
  for (int ms = 0; ms < 2; ++ms)
#pragma unroll
    for (int ks = 0; ks < 2; ++ks)
      aq[ms][ks] = *reinterpret_cast<const short8*>(
          Q + base + (size_t)(qc * 128 + wave * 32 + ms * 16 + m16) * ND + h * 64 + ks * 32 + qd * 8);

  const bf16* kg[2];
  bf16* kl[2];
#pragma unroll
  for (int s = 0; s < 2; ++s) {
    int i = wave * 2 + s;
    int row = i * 8 + (lane >> 3);
    int sg = (lane & 7) ^ (row & 7);
    kg[s] = K + base + (size_t)row * ND + h * 64 + sg * 8;
    kl[s] = Ks + i * 512;
  }

  floatx4 oa[4][2];
  const floatx4 zero = {0.f, 0.f, 0.f, 0.f};
#pragma unroll
  for (int i = 0; i < 4; ++i)
#pragma unroll
    for (int j = 0; j < 2; ++j) oa[i][j] = zero;
  float lsum[2][4];
#pragma unroll
  for (int i = 0; i < 2; ++i)
#pragma unroll
    for (int r = 0; r < 4; ++r) lsum[i][r] = 0.f;

  for (int kc = 0; kc < 8; ++kc) {
    __syncthreads();
#pragma unroll
    for (int s = 0; s < 2; ++s) async_copy16(kl[s], kg[s] + (size_t)(kc * 64) * ND);
    __syncthreads();
    floatx4 sc[2][4];
#pragma unroll
    for (int i = 0; i < 2; ++i)
#pragma unroll
      for (int j = 0; j < 4; ++j) sc[i][j] = zero;
#pragma unroll
    for (int ks = 0; ks < 2; ++ks)
#pragma unroll
      for (int n = 0; n < 4; ++n) {
        int row = n * 16 + m16;
        int phys = (ks * 4 + qd) ^ (row & 7);
        short8 bk = *reinterpret_cast<const short8*>(Ks + row * 64 + phys * 8);
#pragma unroll
        for (int ms = 0; ms < 2; ++ms)
          sc[ms][n] = __builtin_amdgcn_mfma_f32_16x16x32_bf16(aq[ms][ks], bk, sc[ms][n], 0, 0, 0);
      }
#pragma unroll
    for (int ms = 0; ms < 2; ++ms)
#pragma unroll
      for (int n = 0; n < 4; ++n)
#pragma unroll
        for (int r = 0; r < 4; ++r) {
          float p = __expf(sc[ms][n][r] * 0.125f);
          lsum[ms][r] += p;
          Ps[wave][ms * 16 + qd * 4 + r][n * 16 + m16] = f2bf(p);
        }
#pragma unroll
    for (int ks = 0; ks < 2; ++ks) {
      short8 bp[2];
#pragma unroll
      for (int j = 0; j < 2; ++j)
        bp[j] = *reinterpret_cast<const short8*>(&Ps[wave][j * 16 + m16][ks * 32 + qd * 8]);
#pragma unroll
      for (int i = 0; i < 4; ++i) {
        short8 av = *reinterpret_cast<const short8*>(
            Vt + baseT + (size_t)(h * 64 + i * 16 + m16) * NC + kc * 64 + ks * 32 + qd * 8);
#pragma unroll
        for (int j = 0; j < 2; ++j)
          oa[i][j] = __builtin_amdgcn_mfma_f32_16x16x32_bf16(av, bp[j], oa[i][j], 0, 0, 0);
      }
    }
  }
#pragma unroll
  for (int ms = 0; ms < 2; ++ms)
#pragma unroll
    for (int r = 0; r < 4; ++r) {
      float t = lsum[ms][r];
      t += __shfl_xor(t, 1, 64);
      t += __shfl_xor(t, 2, 64);
      t += __shfl_xor(t, 4, 64);
      t += __shfl_xor(t, 8, 64);
      if (m16 == 0) linvS[wave][ms * 16 + qd * 4 + r] = 1.f / t;
    }
  __syncthreads();
  float lsc[2];
#pragma unroll
  for (int j = 0; j < 2; ++j) lsc[j] = linvS[wave][j * 16 + m16];
#pragma unroll
  for (int i = 0; i < 4; ++i) {
    int drow = h * 64 + i * 16 + qd * 4;
#pragma unroll
    for (int j = 0; j < 2; ++j) {
      int qcol = qc * 128 + wave * 32 + j * 16 + m16;
#pragma unroll
      for (int r = 0; r < 4; ++r)
        OT[baseT + (size_t)(drow + r) * NC + qcol] = f2bf(oa[i][j][r] * lsc[j]);
    }
  }
}

// ---- GEMM C = A(MxK) * Bt(NxK)^T, bf16 k-contiguous, global_load_lds staging.
__global__ __launch_bounds__(256, 3) void k_gemm_bt(const bf16* __restrict__ A,
                                                    const bf16* __restrict__ Bt,
                                                    const float* __restrict__ bias,
                                                    void* __restrict__ Y,
                                                    int Kdim, int Ndim, int mode) {
  __shared__ __align__(16) bf16 As[128 * 32];
  __shared__ __align__(16) bf16 Bs[128 * 32];
  const int n0 = blockIdx.x * 128, m0 = blockIdx.y * 128;
  const int tid = threadIdx.x, lane = tid & 63, wave = tid >> 6;
  const int wm = (wave & 1) * 64, wn = (wave >> 1) * 64;
  const int m16 = lane & 15, qd = lane >> 4;

  const bf16* gb[4];
  bf16* lb[4];
#pragma unroll
  for (int idx = 0; idx < 4; ++idx) {
    int s = wave + idx * 4;
    int which = s >> 3;
    int i8 = s & 7;
    int row = i8 * 16 + (lane >> 2);
    int sg = (lane & 3) ^ ((row >> 1) & 3);
    const bf16* src = which ? (Bt + (size_t)(n0 + row) * Kdim) : (A + (size_t)(m0 + row) * Kdim);
    gb[idx] = src + sg * 8;
    lb[idx] = (which ? Bs : As) + i8 * 512;
  }

  floatx4 acc[4][4];
  const floatx4 zero = {0.f, 0.f, 0.f, 0.f};
#pragma unroll
  for (int i = 0; i < 4; ++i)
#pragma unroll
    for (int j = 0; j < 4; ++j) acc[i][j] = zero;

  for (int ks = 0; ks < Kdim / 32; ++ks) {
    __syncthreads();
#pragma unroll
    for (int idx = 0; idx < 4; ++idx) async_copy16(lb[idx], gb[idx] + ks * 32);
    __syncthreads();
    short8 af[4], bfv[4];
#pragma unroll
    for (int i = 0; i < 4; ++i) {
      int ra = wm + i * 16 + m16;
      af[i] = *reinterpret_cast<const short8*>(As + ra * 32 + (qd ^ ((ra >> 1) & 3)) * 8);
      int rb = wn + i * 16 + m16;
      bfv[i] = *reinterpret_cast<const short8*>(Bs + rb * 32 + (qd ^ ((rb >> 1) & 3)) * 8);
    }
#pragma unroll
    for (int j = 0; j < 4; ++j)
#pragma unroll
      for (int i = 0; i < 4; ++i)
        acc[i][j] = __builtin_amdgcn_mfma_f32_16x16x32_bf16(af[i], bfv[j], acc[i][j], 0, 0, 0);
  }
#pragma unroll
  for (int i = 0; i < 4; ++i) {
    int m = m0 + wm + i * 16 + qd * 4;
#pragma unroll
    for (int j = 0; j < 4; ++j) {
      int n = n0 + wn + j * 16 + m16;
      float bv = bias[n];
#pragma unroll
      for (int r = 0; r < 4; ++r) {
        float v = acc[i][j][r] + bv;
        size_t idx = (size_t)(m + r) * Ndim + n;
        if (mode == 0)
          ((bf16*)Y)[idx] = f2bf(fmaxf(v, 0.f));
        else
          ((float*)Y)[idx] = 2.f * v;
      }
    }
  }
}

extern "C" void kernel_launch(void* const* d_in, const int* in_sizes, int n_in,
                              void* d_out, int out_size, void* d_ws, size_t ws_size,
                              hipStream_t stream) {
  (void)in_sizes; (void)n_in; (void)out_size; (void)ws_size;
  const float* x         = (const float*)d_in[0];
  const float* w_conv_in = (const float*)d_in[1];
  const float* b_conv_in = (const float*)d_in[2];
  const float* wq        = (const float*)d_in[3];
  const float* bq        = (const float*)d_in[4];
  const float* wk        = (const float*)d_in[5];
  const float* bk        = (const float*)d_in[6];
  const float* wv        = (const float*)d_in[7];
  const float* bv        = (const float*)d_in[8];
  const float* wo        = (const float*)d_in[9];
  const float* bo        = (const float*)d_in[10];
  const float* ln0_g     = (const float*)d_in[11];
  const float* ln0_b     = (const float*)d_in[12];
  const float* ln1_g     = (const float*)d_in[13];
  const float* ln1_b     = (const float*)d_in[14];
  const float* w1        = (const float*)d_in[15];
  const float* b1        = (const float*)d_in[16];
  const float* w2        = (const float*)d_in[17];
  const float* b2        = (const float*)d_in[18];

  char* ws = (char*)d_ws;
  const size_t ZP  = 262144;                     // zero page (staging OOB redirect target)
  const size_t WT  = (size_t)KW * NC * NC * 2;
  const size_t W1T = (size_t)NFF * ND * 2;
  const size_t ACT = (size_t)NB * NC * ND * 2;
  size_t off = 0;
  bf16* zp    = (bf16*)(ws + off); off += ZP;
  bf16* wt_in = (bf16*)(ws + off); off += WT;
  bf16* wt_q  = (bf16*)(ws + off); off += WT;
  bf16* wt_k  = (bf16*)(ws + off); off += WT;
  bf16* wt_v  = (bf16*)(ws + off); off += WT;
  bf16* wt_o  = (bf16*)(ws + off); off += WT;
  bf16* w1t   = (bf16*)(ws + off); off += W1T;
  bf16* w2t   = (bf16*)(ws + off); off += W1T;
  bf16* T1    = (bf16*)(ws + off); off += ACT;  // xT -> K
  bf16* T2    = (bf16*)(ws + off); off += ACT;  // qiT -> hn
  bf16* T3    = (bf16*)(ws + off); off += ACT;  // xnT -> aoT
  bf16* T4    = (bf16*)(ws + off); off += ACT;  // Q -> h1
  bf16* T5    = (bf16*)(ws + off); off += ACT;  // Vt
  bf16* mid   = (bf16*)(ws + off); off += (size_t)NB * NC * NFF * 2;

  hipMemsetAsync(zp, 0, ZP, stream);

  // weight prep
  k_transpose_w<<<1024, 256, 0, stream>>>(w_conv_in, wt_in);
  k_transpose_w<<<1024, 256, 0, stream>>>(wq, wt_q);
  k_transpose_w<<<1024, 256, 0, stream>>>(wk, wt_k);
  k_transpose_w<<<1024, 256, 0, stream>>>(wv, wt_v);
  k_transpose_w<<<1024, 256, 0, stream>>>(wo, wt_o);
  k_transpose2d<<<dim3(NFF / 32, ND / 32, 1), 256, 0, stream>>>(w1, w1t, ND, NFF);
  k_transpose2d<<<dim3(ND / 32, NFF / 32, 1), 256, 0, stream>>>(w2, w2t, NFF, ND);
  // xT[b][d][c] from x[b][c][d]
  k_transpose2d<<<dim3(ND / 32, NC / 32, NB), 256, 0, stream>>>(x, T1, NC, ND);

  dim3 cgrid(ND / 128, NC / 128, NB);
  // query_in^T (transposed out)
  k_conv<true><<<cgrid, 256, 0, stream>>>(T1, wt_in, b_conv_in, T2, 1.f, zp);
  // xn^T = colLN(query_in^T)
  k_layernorm_col<<<dim3(NC / 256, NB), 256, 0, stream>>>(T2, ln0_g, ln0_b, T3);
  // Q (normal), K (normal), Vt (transposed)
  k_conv<false><<<cgrid, 256, 0, stream>>>(T2, wt_q, bq, T4, 1.f, zp);
  k_conv<false><<<cgrid, 256, 0, stream>>>(T3, wt_k, bk, T1, 1.f, zp);
  k_conv<true><<<cgrid, 256, 0, stream>>>(T3, wt_v, bv, T5, 1.f, zp);
  // attn -> O^T
  k_attention<<<dim3(NC / 128, 8, NB), 256, 0, stream>>>(T4, T1, T5, T3);
  // h1 = 2*(conv_o(O^T) + bo)  (normal out)
  k_conv<false><<<cgrid, 256, 0, stream>>>(T3, wt_o, bo, T4, 2.f, zp);
  // hn = rowLN(h1)
  k_layernorm<<<NB * NC / 4, 256, 0, stream>>>(T4, ln1_g, ln1_b, T2);
  // ffn
  k_gemm_bt<<<dim3(NFF / 128, NB * NC / 128), 256, 0, stream>>>(T2, w1t, b1, mid, ND, NFF, 0);
  k_gemm_bt<<<dim3(ND / 128, NB * NC / 128), 256, 0, stream>>>(mid, w2t, b2, d_out, NFF, ND, 1);
}

// Round 4
// 570.732 us; speedup vs baseline: 4.0717x; 1.1193x over previous
//
#include <hip/hip_runtime.h>
#include <hip/hip_bf16.h>

typedef __hip_bfloat16 bf16;
typedef __attribute__((ext_vector_type(8))) short short8;
typedef __attribute__((ext_vector_type(4))) float floatx4;

#define NB 32
#define NC 512   // channels / attention sequence axis
#define ND 512   // spatial / feature axis (conv dim, LN dim)
#define NDH 64
#define NFF 2048
#define KW 7

__device__ __forceinline__ float bf2f(bf16 v) { return __bfloat162float(v); }
__device__ __forceinline__ bf16 f2bf(float f) { return __float2bfloat16(f); }

typedef __attribute__((address_space(3))) unsigned lds_u32;
typedef __attribute__((address_space(1))) const unsigned glb_u32;
// async 16B/lane global->LDS; lds dest = wave-uniform base + lane*16
__device__ __forceinline__ void async_copy16(void* lds_dst, const void* gsrc) {
  __builtin_amdgcn_global_load_lds((glb_u32*)gsrc, (lds_u32*)lds_dst, 16, 0, 0);
}

// ---- fused conv-weight transpose for all 5 conv weights (coalesced).
// Block = one co row of one weight: load w[co][*][*] (3584 f32, coalesced)
// into LDS, emit wt[t][co][ci] bf16 (coalesced 4B/lane per tap).
__global__ __launch_bounds__(256) void k_transpose_w_all(
    const float* __restrict__ w0, const float* __restrict__ w1,
    const float* __restrict__ w2, const float* __restrict__ w3,
    const float* __restrict__ w4, bf16* __restrict__ t0, bf16* __restrict__ t1,
    bf16* __restrict__ t2, bf16* __restrict__ t3, bf16* __restrict__ t4) {
  __shared__ float row[NC * KW];
  const int co = blockIdx.x;
  const int which = blockIdx.y;
  const float* w = which == 0 ? w0 : which == 1 ? w1 : which == 2 ? w2 : which == 3 ? w3 : w4;
  bf16* wt = which == 0 ? t0 : which == 1 ? t1 : which == 2 ? t2 : which == 3 ? t3 : t4;
  const int tid = threadIdx.x;
  const float* src = w + (size_t)co * NC * KW;
#pragma unroll
  for (int i = 0; i < 14; ++i) row[tid + i * 256] = src[tid + i * 256];
  __syncthreads();
  const int ci = tid * 2;
#pragma unroll
  for (int t = 0; t < KW; ++t) {
    bf16 a = f2bf(row[ci * KW + t]);
    bf16 b = f2bf(row[ci * KW + KW + t]);
    bf16* dst = wt + (size_t)t * NC * NC + (size_t)co * NC + ci;
    dst[0] = a;
    dst[1] = b;
  }
}

// ---- batched 2D transpose f32 -> bf16 : dst[z][c][r] = src[z][r][c]
__global__ __launch_bounds__(256) void k_transpose2d(const float* __restrict__ src,
                                                     bf16* __restrict__ dst,
                                                     int R, int Ccols) {
  __shared__ bf16 t[32][33];
  int bc = blockIdx.x * 32, br = blockIdx.y * 32;
  size_t so = (size_t)blockIdx.z * R * Ccols;
  int tx = threadIdx.x & 31, ty = threadIdx.x >> 5;
#pragma unroll
  for (int i = 0; i < 32; i += 8)
    t[ty + i][tx] = f2bf(src[so + (size_t)(br + ty + i) * Ccols + bc + tx]);
  __syncthreads();
#pragma unroll
  for (int i = 0; i < 32; i += 8)
    dst[so + (size_t)(bc + ty + i) * R + br + tx] = t[tx][ty + i];
}

// ---- causal conv as 7-tap shifted GEMM, both operands staged in LDS (m97 style).
// Input Xt[b][d][ci] (ci-contiguous). Wt[tap][co][ci].
// Block: 128co x 128d, 4 waves 2x2 (wave = 64co x 64d). BK=32 ci, 16 k-steps.
// ~950 TF measured (R3) -- at the m97-structure plateau; do not tweak.
template <bool TRANS_OUT>
__global__ __launch_bounds__(256, 3) void k_conv(const bf16* __restrict__ Xt,
                                                 const bf16* __restrict__ Wt,
                                                 const float* __restrict__ bias,
                                                 bf16* __restrict__ Y, float outScale,
                                                 const bf16* __restrict__ zp) {
  __shared__ __align__(16) bf16 Ws[512 * 32];  // 4 taps x 128 co x 32 ci
  __shared__ __align__(16) bf16 Xs[144 * 32];  // rows: d0-6+r, 64B rows, XOR-swizzled
  const int d0 = blockIdx.x * 128;
  const int co0 = blockIdx.y * 128;
  const int b = blockIdx.z;
  const int tid = threadIdx.x, lane = tid & 63, wave = tid >> 6;
  const int m16 = lane & 15, qd = lane >> 4;
  const int wm = (wave & 1) * 64, wn = (wave >> 1) * 64;
  const int l4 = lane >> 2;
  const int seg = (lane & 3) ^ ((l4 >> 1) & 3);

  const bf16* xb = Xt + (size_t)b * ND * NC;
  const bf16* pw = Wt + (size_t)(co0 + l4) * NC + seg * 8;
  const bf16* pxm = xb + (ptrdiff_t)(d0 - 6 + l4) * NC + seg * 8;
  const bf16* px0 = (d0 == 0 && l4 < 6) ? (zp + seg * 8) : pxm;
  const bf16* px8 = (d0 == 384 && l4 >= 6) ? (zp + seg * 8) : pxm;

  floatx4 acc[4][4];
  const floatx4 zero = {0.f, 0.f, 0.f, 0.f};
#pragma unroll
  for (int i = 0; i < 4; ++i)
#pragma unroll
    for (int j = 0; j < 4; ++j) acc[i][j] = zero;

  const int physW = qd ^ ((m16 >> 1) & 3);

  for (int cs = 0; cs < 16; ++cs) {
    const int ko = cs * 32;
    __syncthreads();
    {
      const bf16* s0 = (wave == 0) ? px0 : pxm;
      async_copy16(Xs + wave * 512, s0 + wave * (16 * NC) + ko);
      async_copy16(Xs + (wave + 4) * 512, pxm + (wave + 4) * (16 * NC) + ko);
      if (wave == 0) async_copy16(Xs + 8 * 512, px8 + 8 * (16 * NC) + ko);
      const bf16* pt = pw + (size_t)wave * NC * NC + ko;
#pragma unroll
      for (int q = 0; q < 8; ++q)
        async_copy16(Ws + (wave * 8 + q) * 512, pt + q * (16 * NC));
    }
    __syncthreads();
#pragma unroll
    for (int t = 0; t < 4; ++t) {
      short8 wf[4], xf[4];
#pragma unroll
      for (int i = 0; i < 4; ++i)
        wf[i] = *reinterpret_cast<const short8*>(Ws + (t * 128 + wm + i * 16 + m16) * 32 + physW * 8);
      int rb = wn + m16 + t;
      int physX = qd ^ ((rb >> 1) & 3);
#pragma unroll
      for (int j = 0; j < 4; ++j)
        xf[j] = *reinterpret_cast<const short8*>(Xs + (rb + j * 16) * 32 + physX * 8);
#pragma unroll
      for (int i = 0; i < 4; ++i)
#pragma unroll
        for (int j = 0; j < 4; ++j)
          acc[i][j] = TRANS_OUT
              ? __builtin_amdgcn_mfma_f32_16x16x32_bf16(xf[j], wf[i], acc[i][j], 0, 0, 0)
              : __builtin_amdgcn_mfma_f32_16x16x32_bf16(wf[i], xf[j], acc[i][j], 0, 0, 0);
    }
    __syncthreads();
#pragma unroll
    for (int k = 0; k < 6; ++k) {
      int s = wave * 6 + k;
      int tl = s >> 3, q = s & 7;
      async_copy16(Ws + s * 512, pw + (size_t)(tl + 4) * NC * NC + q * (16 * NC) + ko);
    }
    __syncthreads();
#pragma unroll
    for (int tl = 0; tl < 3; ++tl) {
      short8 wf[4], xf[4];
#pragma unroll
      for (int i = 0; i < 4; ++i)
        wf[i] = *reinterpret_cast<const short8*>(Ws + (tl * 128 + wm + i * 16 + m16) * 32 + physW * 8);
      int rb = wn + m16 + tl + 4;
      int physX = qd ^ ((rb >> 1) & 3);
#pragma unroll
      for (int j = 0; j < 4; ++j)
        xf[j] = *reinterpret_cast<const short8*>(Xs + (rb + j * 16) * 32 + physX * 8);
#pragma unroll
      for (int i = 0; i < 4; ++i)
#pragma unroll
        for (int j = 0; j < 4; ++j)
          acc[i][j] = TRANS_OUT
              ? __builtin_amdgcn_mfma_f32_16x16x32_bf16(xf[j], wf[i], acc[i][j], 0, 0, 0)
              : __builtin_amdgcn_mfma_f32_16x16x32_bf16(wf[i], xf[j], acc[i][j], 0, 0, 0);
    }
  }

  if (!TRANS_OUT) {
    bf16* yb = Y + (size_t)b * NC * ND;
#pragma unroll
    for (int i = 0; i < 4; ++i) {
      int cobase = co0 + wm + i * 16 + qd * 4;
#pragma unroll
      for (int j = 0; j < 4; ++j) {
        int dcol = d0 + wn + j * 16 + m16;
#pragma unroll
        for (int r = 0; r < 4; ++r) {
          float v = (acc[i][j][r] + bias[cobase + r]) * outScale;
          yb[(size_t)(cobase + r) * ND + dcol] = f2bf(v);
        }
      }
    }
  } else {
    bf16* yb = Y + (size_t)b * ND * NC;
#pragma unroll
    for (int i = 0; i < 4; ++i) {
      int ccol = co0 + wm + i * 16 + m16;
      float bv = bias[ccol];
#pragma unroll
      for (int j = 0; j < 4; ++j) {
        int drow = d0 + wn + j * 16 + qd * 4;
#pragma unroll
        for (int r = 0; r < 4; ++r) {
          float v = (acc[i][j][r] + bv) * outScale;
          yb[(size_t)(drow + r) * NC + ccol] = f2bf(v);
        }
      }
    }
  }
}

// ---- row layernorm over last dim (512)
__global__ __launch_bounds__(256, 4) void k_layernorm(const bf16* __restrict__ x,
                                                      const float* __restrict__ gamma,
                                                      const float* __restrict__ beta,
                                                      bf16* __restrict__ y) {
  int row = blockIdx.x * 4 + (threadIdx.x >> 6);
  int lane = threadIdx.x & 63;
  const bf16* xr = x + (size_t)row * ND + lane * 8;
  uint4 raw = *reinterpret_cast<const uint4*>(xr);
  const bf16* rp = reinterpret_cast<const bf16*>(&raw);
  float v[8];
#pragma unroll
  for (int j = 0; j < 8; ++j) v[j] = bf2f(rp[j]);
  float s = 0.f;
#pragma unroll
  for (int j = 0; j < 8; ++j) s += v[j];
#pragma unroll
  for (int m = 32; m >= 1; m >>= 1) s += __shfl_xor(s, m, 64);
  float mean = s * (1.f / 512.f);
  float ss = 0.f;
#pragma unroll
  for (int j = 0; j < 8; ++j) { float dd = v[j] - mean; ss += dd * dd; }
#pragma unroll
  for (int m = 32; m >= 1; m >>= 1) ss += __shfl_xor(ss, m, 64);
  float rden = 1.f / (sqrtf(ss * (1.f / 511.f)) + 1e-6f);
  __align__(16) bf16 outv[8];
#pragma unroll
  for (int j = 0; j < 8; ++j)
    outv[j] = f2bf(gamma[lane * 8 + j] * (v[j] - mean) * rden + beta[lane * 8 + j]);
  *reinterpret_cast<uint4*>(y + (size_t)row * ND + lane * 8) = *reinterpret_cast<uint4*>(outv);
}

// ---- column layernorm: x[b][d][c], normalize over the 512 d-rows per column c.
// Block = 64 columns; g = t&7 (8 col-octets), sl = t>>3 (32 row-slices x 16).
__global__ __launch_bounds__(256, 4) void k_layernorm_col(const bf16* __restrict__ x,
                                                          const float* __restrict__ gamma,
                                                          const float* __restrict__ beta,
                                                          bf16* __restrict__ y) {
  __shared__ float red[2][32][64];
  __shared__ float mS[64], rS[64];
  const int b = blockIdx.y;
  const int c0 = blockIdx.x * 64;
  const int t = threadIdx.x;
  const int g = t & 7, sl = t >> 3;
  const bf16* xb = x + (size_t)b * ND * NC + c0 + g * 8;
  float fs[8], fq[8];
#pragma unroll
  for (int j = 0; j < 8; ++j) { fs[j] = 0.f; fq[j] = 0.f; }
#pragma unroll
  for (int i = 0; i < 16; ++i) {
    int r = sl * 16 + i;
    uint4 raw = *reinterpret_cast<const uint4*>(xb + (size_t)r * NC);
    const bf16* rp = reinterpret_cast<const bf16*>(&raw);
#pragma unroll
    for (int j = 0; j < 8; ++j) { float v = bf2f(rp[j]); fs[j] += v; fq[j] += v * v; }
  }
#pragma unroll
  for (int j = 0; j < 8; ++j) { red[0][sl][g * 8 + j] = fs[j]; red[1][sl][g * 8 + j] = fq[j]; }
  __syncthreads();
  if (t < 64) {
    float s = 0.f, q = 0.f;
#pragma unroll
    for (int s2 = 0; s2 < 32; ++s2) { s += red[0][s2][t]; q += red[1][s2][t]; }
    float mean = s * (1.f / 512.f);
    float var = fmaxf((q - 512.f * mean * mean) * (1.f / 511.f), 0.f);
    mS[t] = mean;
    rS[t] = 1.f / (sqrtf(var) + 1e-6f);
  }
  __syncthreads();
  float mv[8], rv[8];
#pragma unroll
  for (int j = 0; j < 8; ++j) { mv[j] = mS[g * 8 + j]; rv[j] = rS[g * 8 + j]; }
  bf16* yb = y + (size_t)b * ND * NC + c0 + g * 8;
#pragma unroll
  for (int i = 0; i < 16; ++i) {
    int r = sl * 16 + i;
    uint4 raw = *reinterpret_cast<const uint4*>(xb + (size_t)r * NC);
    const bf16* rp = reinterpret_cast<const bf16*>(&raw);
    float gr = gamma[r], br = beta[r];
    __align__(16) bf16 ov[8];
#pragma unroll
    for (int j = 0; j < 8; ++j) ov[j] = f2bf(gr * (bf2f(rp[j]) - mv[j]) * rv[j] + br);
    *reinterpret_cast<uint4*>(yb + (size_t)r * NC) = *reinterpret_cast<uint4*>(ov);
  }
}

// ---- attention: Q,K normal [c][d]; Vt transposed [d][c]; output O^T [d][c].
// K AND V chunks both staged via global_load_lds (no in-loop per-lane global).
__global__ __launch_bounds__(256, 3) void k_attention(const bf16* __restrict__ Q,
                                                      const bf16* __restrict__ K,
                                                      const bf16* __restrict__ Vt,
                                                      bf16* __restrict__ OT) {
  __shared__ __align__(16) bf16 Ks[64 * 64];   // [key][dh]
  __shared__ __align__(16) bf16 Vs[64 * 64];   // [dh][key]
  __shared__ __align__(16) bf16 Ps[4][32][72];
  __shared__ float linvS[4][32];
  const int qc = blockIdx.x, h = blockIdx.y, b = blockIdx.z;
  const int tid = threadIdx.x, lane = tid & 63, wave = tid >> 6;
  const int m16 = lane & 15, qd = lane >> 4;
  const size_t base = (size_t)b * NC * ND;
  const size_t baseT = (size_t)b * ND * NC;

  short8 aq[2][2];
#pragma unroll
  for (int ms = 0; ms < 2; ++ms)
#pragma unroll
    for (int ks = 0; ks < 2; ++ks)
      aq[ms][ks] = *reinterpret_cast<const short8*>(
          Q + base + (size_t)(qc * 128 + wave * 32 + ms * 16 + m16) * ND + h * 64 + ks * 32 + qd * 8);

  // staging descriptors: K rows stride ND (key-major), V rows stride NC (dh-major)
  const bf16* kg[2];
  bf16* kl[2];
  const bf16* vg[2];
  bf16* vl[2];
#pragma unroll
  for (int s = 0; s < 2; ++s) {
    int i = wave * 2 + s;
    int row = i * 8 + (lane >> 3);
    int sg = (lane & 7) ^ (row & 7);
    kg[s] = K + base + (size_t)row * ND + h * 64 + sg * 8;
    kl[s] = Ks + i * 512;
    vg[s] = Vt + baseT + (size_t)(h * 64 + row) * NC + sg * 8;
    vl[s] = Vs + i * 512;
  }

  floatx4 oa[4][2];
  const floatx4 zero = {0.f, 0.f, 0.f, 0.f};
#pragma unroll
  for (int i = 0; i < 4; ++i)
#pragma unroll
    for (int j = 0; j < 2; ++j) oa[i][j] = zero;
  float lsum[2][4];
#pragma unroll
  for (int i = 0; i < 2; ++i)
#pragma unroll
    for (int r = 0; r < 4; ++r) lsum[i][r] = 0.f;

  for (int kc = 0; kc < 8; ++kc) {
    __syncthreads();
#pragma unroll
    for (int s = 0; s < 2; ++s) {
      async_copy16(kl[s], kg[s] + (size_t)(kc * 64) * ND);
      async_copy16(vl[s], vg[s] + kc * 64);
    }
    __syncthreads();
    floatx4 sc[2][4];
#pragma unroll
    for (int i = 0; i < 2; ++i)
#pragma unroll
      for (int j = 0; j < 4; ++j) sc[i][j] = zero;
#pragma unroll
    for (int ks = 0; ks < 2; ++ks)
#pragma unroll
      for (int n = 0; n < 4; ++n) {
        int row = n * 16 + m16;
        int phys = (ks * 4 + qd) ^ (row & 7);
        short8 bk = *reinterpret_cast<const short8*>(Ks + row * 64 + phys * 8);
#pragma unroll
        for (int ms = 0; ms < 2; ++ms)
          sc[ms][n] = __builtin_amdgcn_mfma_f32_16x16x32_bf16(aq[ms][ks], bk, sc[ms][n], 0, 0, 0);
      }
#pragma unroll
    for (int ms = 0; ms < 2; ++ms)
#pragma unroll
      for (int n = 0; n < 4; ++n)
#pragma unroll
        for (int r = 0; r < 4; ++r) {
          float p = __expf(sc[ms][n][r] * 0.125f);
          lsum[ms][r] += p;
          Ps[wave][ms * 16 + qd * 4 + r][n * 16 + m16] = f2bf(p);
        }
#pragma unroll
    for (int ks = 0; ks < 2; ++ks) {
      short8 bp[2];
#pragma unroll
      for (int j = 0; j < 2; ++j)
        bp[j] = *reinterpret_cast<const short8*>(&Ps[wave][j * 16 + m16][ks * 32 + qd * 8]);
#pragma unroll
      for (int i = 0; i < 4; ++i) {
        int row = i * 16 + m16;
        int phys = (ks * 4 + qd) ^ (row & 7);
        short8 av = *reinterpret_cast<const short8*>(Vs + row * 64 + phys * 8);
#pragma unroll
        for (int j = 0; j < 2; ++j)
          oa[i][j] = __builtin_amdgcn_mfma_f32_16x16x32_bf16(av, bp[j], oa[i][j], 0, 0, 0);
      }
    }
  }
#pragma unroll
  for (int ms = 0; ms < 2; ++ms)
#pragma unroll
    for (int r = 0; r < 4; ++r) {
      float t = lsum[ms][r];
      t += __shfl_xor(t, 1, 64);
      t += __shfl_xor(t, 2, 64);
      t += __shfl_xor(t, 4, 64);
      t += __shfl_xor(t, 8, 64);
      if (m16 == 0) linvS[wave][ms * 16 + qd * 4 + r] = 1.f / t;
    }
  __syncthreads();
  float lsc[2];
#pragma unroll
  for (int j = 0; j < 2; ++j) lsc[j] = linvS[wave][j * 16 + m16];
#pragma unroll
  for (int i = 0; i < 4; ++i) {
    int drow = h * 64 + i * 16 + qd * 4;
#pragma unroll
    for (int j = 0; j < 2; ++j) {
      int qcol = qc * 128 + wave * 32 + j * 16 + m16;
#pragma unroll
      for (int r = 0; r < 4; ++r)
        OT[baseT + (size_t)(drow + r) * NC + qcol] = f2bf(oa[i][j][r] * lsc[j]);
    }
  }
}

// ---- GEMM C = A(MxK) * Bt(NxK)^T, bf16 k-contiguous, global_load_lds staging.
__global__ __launch_bounds__(256, 3) void k_gemm_bt(const bf16* __restrict__ A,
                                                    const bf16* __restrict__ Bt,
                                                    const float* __restrict__ bias,
                                                    void* __restrict__ Y,
                                                    int Kdim, int Ndim, int mode) {
  __shared__ __align__(16) bf16 As[128 * 32];
  __shared__ __align__(16) bf16 Bs[128 * 32];
  const int n0 = blockIdx.x * 128, m0 = blockIdx.y * 128;
  const int tid = threadIdx.x, lane = tid & 63, wave = tid >> 6;
  const int wm = (wave & 1) * 64, wn = (wave >> 1) * 64;
  const int m16 = lane & 15, qd = lane >> 4;

  const bf16* gb[4];
  bf16* lb[4];
#pragma unroll
  for (int idx = 0; idx < 4; ++idx) {
    int s = wave + idx * 4;
    int which = s >> 3;
    int i8 = s & 7;
    int row = i8 * 16 + (lane >> 2);
    int sg = (lane & 3) ^ ((row >> 1) & 3);
    const bf16* src = which ? (Bt + (size_t)(n0 + row) * Kdim) : (A + (size_t)(m0 + row) * Kdim);
    gb[idx] = src + sg * 8;
    lb[idx] = (which ? Bs : As) + i8 * 512;
  }

  floatx4 acc[4][4];
  const floatx4 zero = {0.f, 0.f, 0.f, 0.f};
#pragma unroll
  for (int i = 0; i < 4; ++i)
#pragma unroll
    for (int j = 0; j < 4; ++j) acc[i][j] = zero;

  for (int ks = 0; ks < Kdim / 32; ++ks) {
    __syncthreads();
#pragma unroll
    for (int idx = 0; idx < 4; ++idx) async_copy16(lb[idx], gb[idx] + ks * 32);
    __syncthreads();
    short8 af[4], bfv[4];
#pragma unroll
    for (int i = 0; i < 4; ++i) {
      int ra = wm + i * 16 + m16;
      af[i] = *reinterpret_cast<const short8*>(As + ra * 32 + (qd ^ ((ra >> 1) & 3)) * 8);
      int rb = wn + i * 16 + m16;
      bfv[i] = *reinterpret_cast<const short8*>(Bs + rb * 32 + (qd ^ ((rb >> 1) & 3)) * 8);
    }
#pragma unroll
    for (int j = 0; j < 4; ++j)
#pragma unroll
      for (int i = 0; i < 4; ++i)
        acc[i][j] = __builtin_amdgcn_mfma_f32_16x16x32_bf16(af[i], bfv[j], acc[i][j], 0, 0, 0);
  }
#pragma unroll
  for (int i = 0; i < 4; ++i) {
    int m = m0 + wm + i * 16 + qd * 4;
#pragma unroll
    for (int j = 0; j < 4; ++j) {
      int n = n0 + wn + j * 16 + m16;
      float bv = bias[n];
#pragma unroll
      for (int r = 0; r < 4; ++r) {
        float v = acc[i][j][r] + bv;
        size_t idx = (size_t)(m + r) * Ndim + n;
        if (mode == 0)
          ((bf16*)Y)[idx] = f2bf(fmaxf(v, 0.f));
        else
          ((float*)Y)[idx] = 2.f * v;
      }
    }
  }
}

extern "C" void kernel_launch(void* const* d_in, const int* in_sizes, int n_in,
                              void* d_out, int out_size, void* d_ws, size_t ws_size,
                              hipStream_t stream) {
  (void)in_sizes; (void)n_in; (void)out_size; (void)ws_size;
  const float* x         = (const float*)d_in[0];
  const float* w_conv_in = (const float*)d_in[1];
  const float* b_conv_in = (const float*)d_in[2];
  const float* wq        = (const float*)d_in[3];
  const float* bq        = (const float*)d_in[4];
  const float* wk        = (const float*)d_in[5];
  const float* bk        = (const float*)d_in[6];
  const float* wv        = (const float*)d_in[7];
  const float* bv        = (const float*)d_in[8];
  const float* wo        = (const float*)d_in[9];
  const float* bo        = (const float*)d_in[10];
  const float* ln0_g     = (const float*)d_in[11];
  const float* ln0_b     = (const float*)d_in[12];
  const float* ln1_g     = (const float*)d_in[13];
  const float* ln1_b     = (const float*)d_in[14];
  const float* w1        = (const float*)d_in[15];
  const float* b1        = (const float*)d_in[16];
  const float* w2        = (const float*)d_in[17];
  const float* b2        = (const float*)d_in[18];

  char* ws = (char*)d_ws;
  const size_t ZP  = 262144;
  const size_t WT  = (size_t)KW * NC * NC * 2;
  const size_t W1T = (size_t)NFF * ND * 2;
  const size_t ACT = (size_t)NB * NC * ND * 2;
  size_t off = 0;
  bf16* zp    = (bf16*)(ws + off); off += ZP;
  bf16* wt_in = (bf16*)(ws + off); off += WT;
  bf16* wt_q  = (bf16*)(ws + off); off += WT;
  bf16* wt_k  = (bf16*)(ws + off); off += WT;
  bf16* wt_v  = (bf16*)(ws + off); off += WT;
  bf16* wt_o  = (bf16*)(ws + off); off += WT;
  bf16* w1t   = (bf16*)(ws + off); off += W1T;
  bf16* w2t   = (bf16*)(ws + off); off += W1T;
  bf16* T1    = (bf16*)(ws + off); off += ACT;  // xT -> K
  bf16* T2    = (bf16*)(ws + off); off += ACT;  // qiT -> hn
  bf16* T3    = (bf16*)(ws + off); off += ACT;  // xnT -> aoT
  bf16* T4    = (bf16*)(ws + off); off += ACT;  // Q -> h1
  bf16* T5    = (bf16*)(ws + off); off += ACT;  // Vt
  bf16* mid   = (bf16*)(ws + off); off += (size_t)NB * NC * NFF * 2;

  hipMemsetAsync(zp, 0, ZP, stream);

  // weight prep (single fused launch for all 5 conv weights)
  k_transpose_w_all<<<dim3(NC, 5), 256, 0, stream>>>(
      w_conv_in, wq, wk, wv, wo, wt_in, wt_q, wt_k, wt_v, wt_o);
  k_transpose2d<<<dim3(NFF / 32, ND / 32, 1), 256, 0, stream>>>(w1, w1t, ND, NFF);
  k_transpose2d<<<dim3(ND / 32, NFF / 32, 1), 256, 0, stream>>>(w2, w2t, NFF, ND);
  // xT[b][d][c] from x[b][c][d]
  k_transpose2d<<<dim3(ND / 32, NC / 32, NB), 256, 0, stream>>>(x, T1, NC, ND);

  dim3 cgrid(ND / 128, NC / 128, NB);
  // query_in^T (transposed out)
  k_conv<true><<<cgrid, 256, 0, stream>>>(T1, wt_in, b_conv_in, T2, 1.f, zp);
  // xn^T = colLN(query_in^T)
  k_layernorm_col<<<dim3(NC / 64, NB), 256, 0, stream>>>(T2, ln0_g, ln0_b, T3);
  // Q (normal), K (normal), Vt (transposed)
  k_conv<false><<<cgrid, 256, 0, stream>>>(T2, wt_q, bq, T4, 1.f, zp);
  k_conv<false><<<cgrid, 256, 0, stream>>>(T3, wt_k, bk, T1, 1.f, zp);
  k_conv<true><<<cgrid, 256, 0, stream>>>(T3, wt_v, bv, T5, 1.f, zp);
  // attn -> O^T
  k_attention<<<dim3(NC / 128, 8, NB), 256, 0, stream>>>(T4, T1, T5, T3);
  // h1 = 2*(conv_o(O^T) + bo)  (normal out)
  k_conv<false><<<cgrid, 256, 0, stream>>>(T3, wt_o, bo, T4, 2.f, zp);
  // hn = rowLN(h1)
  k_layernorm<<<NB * NC / 4, 256, 0, stream>>>(T4, ln1_g, ln1_b, T2);
  // ffn
  k_gemm_bt<<<dim3(NFF / 128, NB * NC / 128), 256, 0, stream>>>(T2, w1t, b1, mid, ND, NFF, 0);
  k_gemm_bt<<<dim3(ND / 128, NB * NC / 128), 256, 0, stream>>>(mid, w2t, b2, d_out, NFF, ND, 1);
}